// Round 1
// baseline (1062.442 us; speedup 1.0000x reference)
//
#include <hip/hip_runtime.h>
#include <math.h>

#define NEG_SLOPE 0.2f
#define EPS_F 1e-16f
typedef long long ll;

// ---------------- edge dtype detection (int64 vs int32) ----------------
__global__ void detect_int64_kernel(const unsigned int* __restrict__ w, int E,
                                    int* __restrict__ flag) {
  __shared__ int nz;
  if (threadIdx.x == 0) nz = 0;
  __syncthreads();
  int cnt = E < 2048 ? E : 2048;
  int local = 0;
  for (int i = threadIdx.x; i < cnt; i += blockDim.x)
    if (w[2 * i + 1] != 0u) local++;
  if (local) atomicAdd(&nz, local);
  __syncthreads();
  if (threadIdx.x == 0) *flag = (nz == 0) ? 1 : 0;  // 1 => int64 layout
}

__device__ __forceinline__ void edge_at(const int* __restrict__ ew, int E, int e,
                                        int is64, int& s, int& d) {
  if (is64) { s = ew[2 * e]; d = ew[2 * E + 2 * e]; }
  else      { s = ew[e];     d = ew[E + e]; }
}

// ---------------- CSR build ----------------
__global__ void init_deg_kernel(int* deg, int N) {
  int i = blockIdx.x * blockDim.x + threadIdx.x;
  if (i < N) deg[i] = 1;  // self loop
}

__global__ void count_deg_kernel(const int* __restrict__ ew, int E, int* deg,
                                 const int* __restrict__ flag) {
  int is64 = *flag;
  int e = blockIdx.x * blockDim.x + threadIdx.x;
  if (e < E) {
    int s, d;
    edge_at(ew, E, e, is64, s, d);
    atomicAdd(&deg[d], 1);
  }
}

__global__ void scan_kernel(const int* __restrict__ deg, int* rowptr, int* cursor, int N) {
  __shared__ int sums[1024];
  int tid = threadIdx.x;
  int chunk = (N + 1023) >> 10;
  int start = tid * chunk;
  int end = start + chunk; if (end > N) end = N;
  int s = 0;
  for (int i = start; i < end; ++i) s += deg[i];
  sums[tid] = s;
  __syncthreads();
  for (int off = 1; off < 1024; off <<= 1) {
    int v = (tid >= off) ? sums[tid - off] : 0;
    __syncthreads();
    sums[tid] += v;
    __syncthreads();
  }
  int run = (tid == 0) ? 0 : sums[tid - 1];
  for (int i = start; i < end; ++i) {
    rowptr[i] = run; cursor[i] = run;
    run += deg[i];
  }
  if (tid == 1023) rowptr[N] = sums[1023];
}

__global__ void fill_kernel(const int* __restrict__ ew, int E, int N, int* cursor,
                            int* csr, const int* __restrict__ flag) {
  int is64 = *flag;
  int i = blockIdx.x * blockDim.x + threadIdx.x;
  if (i < E) {
    int s, d;
    edge_at(ew, E, i, is64, s, d);
    int pos = atomicAdd(&cursor[d], 1);
    csr[pos] = s;
  } else if (i < E + N) {
    int n = i - E;
    int pos = atomicAdd(&cursor[n], 1);
    csr[pos] = n;
  }
}

// ---------------- fp32 tiled GEMM: C[M,N] = A[M,K] * B[K,N] ----------------
#define BM 128
#define BN 64
#define BK 16

__global__ __launch_bounds__(256) void gemm_kernel(
    const float* __restrict__ A, const float* __restrict__ B, float* __restrict__ C,
    int M, int N, int K) {
  __shared__ float As[BK][BM + 4];
  __shared__ float Bs[BK][BN + 4];
  int tid = threadIdx.x;
  int bm = blockIdx.y * BM;
  int bn = blockIdx.x * BN;
  int ty = tid >> 4, tx = tid & 15;
  float acc[8][4];
#pragma unroll
  for (int i = 0; i < 8; ++i)
#pragma unroll
    for (int j = 0; j < 4; ++j) acc[i][j] = 0.f;

  int arow = tid >> 1;        // 0..127
  int ak0 = (tid & 1) * 8;    // 0 or 8
  int brow = tid >> 4;        // 0..15
  int bn0 = (tid & 15) * 4;   // 0..60

  int ga_row = bm + arow; if (ga_row >= M) ga_row = M - 1;  // clamp; unsaved rows
  const float* aptr = A + (ll)ga_row * K + ak0;
  const float* bptr = B + (ll)brow * N + bn + bn0;

  for (int kt = 0; kt < K; kt += BK) {
    float4 a0 = *(const float4*)(aptr + kt);
    float4 a1 = *(const float4*)(aptr + kt + 4);
    float4 bv = *(const float4*)(bptr + (ll)kt * N);
    As[ak0 + 0][arow] = a0.x; As[ak0 + 1][arow] = a0.y;
    As[ak0 + 2][arow] = a0.z; As[ak0 + 3][arow] = a0.w;
    As[ak0 + 4][arow] = a1.x; As[ak0 + 5][arow] = a1.y;
    As[ak0 + 6][arow] = a1.z; As[ak0 + 7][arow] = a1.w;
    *(float4*)&Bs[brow][bn0] = bv;
    __syncthreads();
#pragma unroll
    for (int k = 0; k < BK; ++k) {
      float a[8], b[4];
      *(float4*)&a[0] = *(const float4*)&As[k][ty * 8];
      *(float4*)&a[4] = *(const float4*)&As[k][ty * 8 + 4];
      *(float4*)&b[0] = *(const float4*)&Bs[k][tx * 4];
#pragma unroll
      for (int i = 0; i < 8; ++i)
#pragma unroll
        for (int j = 0; j < 4; ++j)
          acc[i][j] = fmaf(a[i], b[j], acc[i][j]);
    }
    __syncthreads();
  }
#pragma unroll
  for (int i = 0; i < 8; ++i) {
    int row = bm + ty * 8 + i;
    if (row < M) {
      float4 v = make_float4(acc[i][0], acc[i][1], acc[i][2], acc[i][3]);
      *(float4*)&C[(ll)row * N + bn + tx * 4] = v;
    }
  }
}

// ---------------- per-node attention scores ----------------
__global__ void score_kernel(const float* __restrict__ h, const float* __restrict__ a_src,
                             const float* __restrict__ a_dst, float* __restrict__ s_src,
                             float* __restrict__ s_dst, int N, int dout) {
  int wid = threadIdx.x >> 6;
  int lane = threadIdx.x & 63;
  int row = blockIdx.x * (blockDim.x >> 6) + wid;
  if (row >= N) return;
  const float* hr = h + (ll)row * dout;
  float ss = 0.f, sd = 0.f;
  for (int d = lane; d < dout; d += 64) {
    float v = hr[d];
    ss += v * a_src[d];
    sd += v * a_dst[d];
  }
#pragma unroll
  for (int o = 32; o > 0; o >>= 1) {
    ss += __shfl_down(ss, o, 64);
    sd += __shfl_down(sd, o, 64);
  }
  if (lane == 0) { s_src[row] = ss; s_dst[row] = sd; }
}

// ---------------- segment softmax + weighted aggregation (per node) ----------------
__global__ __launch_bounds__(256) void aggregate_kernel(
    const float* __restrict__ h, const float* __restrict__ ssrc,
    const float* __restrict__ sdst, const int* __restrict__ rowptr,
    const int* __restrict__ csr, const float* __restrict__ bias,
    float* __restrict__ out, int dout, int do_relu) {
  int node = blockIdx.x;
  int tid = threadIdx.x;
  int lane = tid & 63, wid = tid >> 6;
  int rs = rowptr[node], re = rowptr[node + 1];
  float sd = sdst[node];
  __shared__ float red[4];

  // pass 1: max logit
  float m = -1e30f;
  for (int i = rs + tid; i < re; i += 256) {
    float e = ssrc[csr[i]] + sd;
    e = e > 0.f ? e : NEG_SLOPE * e;
    m = fmaxf(m, e);
  }
#pragma unroll
  for (int o = 32; o > 0; o >>= 1) m = fmaxf(m, __shfl_down(m, o, 64));
  if (lane == 0) red[wid] = m;
  __syncthreads();
  m = fmaxf(fmaxf(red[0], red[1]), fmaxf(red[2], red[3]));
  __syncthreads();

  // pass 2: denominator
  float den = 0.f;
  for (int i = rs + tid; i < re; i += 256) {
    float e = ssrc[csr[i]] + sd;
    e = e > 0.f ? e : NEG_SLOPE * e;
    den += __expf(e - m);
  }
#pragma unroll
  for (int o = 32; o > 0; o >>= 1) den += __shfl_down(den, o, 64);
  if (lane == 0) red[wid] = den;
  __syncthreads();
  den = red[0] + red[1] + red[2] + red[3];
  float inv = 1.f / (den + EPS_F);

  // pass 3: weighted accumulate over incoming edges
  float acc[4] = {0.f, 0.f, 0.f, 0.f};
  for (int i = rs; i < re; ++i) {
    int s = csr[i];
    float e = ssrc[s] + sd;
    e = e > 0.f ? e : NEG_SLOPE * e;
    float w = __expf(e - m) * inv;
    const float* hr = h + (ll)s * dout;
#pragma unroll
    for (int j = 0; j < 4; ++j) {
      int d = tid + j * 256;
      if (d < dout) acc[j] += w * hr[d];
    }
  }
#pragma unroll
  for (int j = 0; j < 4; ++j) {
    int d = tid + j * 256;
    if (d < dout) {
      float v = acc[j] + bias[d];
      if (do_relu) v = fmaxf(v, 0.f);
      out[(ll)node * dout + d] = v;
    }
  }
}

// ---------------- row log_softmax (C == blockDim.x) ----------------
__global__ void log_softmax_kernel(const float* __restrict__ in, float* __restrict__ out,
                                   int C) {
  int row = blockIdx.x;
  int tid = threadIdx.x;
  int lane = tid & 63, wid = tid >> 6;
  __shared__ float red[2];
  float v = in[(ll)row * C + tid];
  float m = v;
#pragma unroll
  for (int o = 32; o > 0; o >>= 1) m = fmaxf(m, __shfl_down(m, o, 64));
  if (lane == 0) red[wid] = m;
  __syncthreads();
  m = fmaxf(red[0], red[1]);
  __syncthreads();
  float ex = __expf(v - m);
  float s = ex;
#pragma unroll
  for (int o = 32; o > 0; o >>= 1) s += __shfl_down(s, o, 64);
  if (lane == 0) red[wid] = s;
  __syncthreads();
  s = red[0] + red[1];
  out[(ll)row * C + tid] = v - m - logf(s);
}

// ---------------- launch ----------------
extern "C" void kernel_launch(void* const* d_in, const int* in_sizes, int n_in,
                              void* d_out, int out_size, void* d_ws, size_t ws_size,
                              hipStream_t stream) {
  const float* x = (const float*)d_in[0];
  const int* ew = (const int*)d_in[1];
  int N = in_sizes[0] / 256;
  int E = in_sizes[1] / 2;

  const float* W[4]  = {(const float*)d_in[2],  (const float*)d_in[6],
                        (const float*)d_in[10], (const float*)d_in[14]};
  const float* Asv[4] = {(const float*)d_in[3],  (const float*)d_in[7],
                         (const float*)d_in[11], (const float*)d_in[15]};
  const float* Adv[4] = {(const float*)d_in[4],  (const float*)d_in[8],
                         (const float*)d_in[12], (const float*)d_in[16]};
  const float* Bv[4] = {(const float*)d_in[5],  (const float*)d_in[9],
                        (const float*)d_in[13], (const float*)d_in[17]};
  const int din[4]  = {256, 1024, 1024, 512};
  const int dout[4] = {1024, 1024, 512, 128};

  char* ws = (char*)d_ws;
  size_t off = 0;
  auto alloc = [&](size_t bytes) {
    void* p = ws + off;
    off += (bytes + 255) & ~(size_t)255;
    return p;
  };
  float* bufA  = (float*)alloc((size_t)N * 1024 * 4);
  float* bufB  = (float*)alloc((size_t)N * 1024 * 4);
  float* s_src = (float*)alloc((size_t)N * 4);
  float* s_dst = (float*)alloc((size_t)N * 4);
  int* deg     = (int*)alloc((size_t)(N + 1) * 4);
  int* rowptr  = (int*)alloc((size_t)(N + 1) * 4);
  int* cursor  = (int*)alloc((size_t)(N + 1) * 4);
  int* csr     = (int*)alloc((size_t)(E + N) * 4);
  int* flag    = (int*)alloc(256);

  detect_int64_kernel<<<1, 256, 0, stream>>>((const unsigned int*)ew, E, flag);
  init_deg_kernel<<<(N + 255) / 256, 256, 0, stream>>>(deg, N);
  count_deg_kernel<<<(E + 255) / 256, 256, 0, stream>>>(ew, E, deg, flag);
  scan_kernel<<<1, 1024, 0, stream>>>(deg, rowptr, cursor, N);
  fill_kernel<<<(E + N + 255) / 256, 256, 0, stream>>>(ew, E, N, cursor, csr, flag);

  for (int l = 0; l < 4; ++l) {
    const float* in = (l == 0) ? x : (const float*)bufB;
    dim3 ggrid(dout[l] / BN, (N + BM - 1) / BM);
    gemm_kernel<<<ggrid, 256, 0, stream>>>(in, W[l], bufA, N, dout[l], din[l]);
    score_kernel<<<(N + 3) / 4, 256, 0, stream>>>(bufA, Asv[l], Adv[l], s_src, s_dst,
                                                  N, dout[l]);
    aggregate_kernel<<<N, 256, 0, stream>>>(bufA, s_src, s_dst, rowptr, csr, Bv[l],
                                            bufB, dout[l], (l < 3) ? 1 : 0);
  }
  log_softmax_kernel<<<N, 128, 0, stream>>>(bufB, (float*)d_out, 128);
}

// Round 2
// 618.151 us; speedup vs baseline: 1.7187x; 1.7187x over previous
//
#include <hip/hip_runtime.h>
#include <math.h>

#define NEG_SLOPE 0.2f
#define EPS_F 1e-16f
typedef long long ll;

typedef __attribute__((ext_vector_type(4))) float f32x4;
typedef __attribute__((ext_vector_type(8))) short bf16x8;

// ---------------- bf16 helpers (bit-level, RTN-even) ----------------
__device__ __forceinline__ unsigned short bf16_of(float f) {
  unsigned u = __float_as_uint(f);
  u += 0x7fffu + ((u >> 16) & 1u);
  return (unsigned short)(u >> 16);
}
__device__ __forceinline__ float bf16_back(unsigned short s) {
  return __uint_as_float((unsigned)s << 16);
}

__device__ __forceinline__ void gload16(const void* g, void* l) {
  __builtin_amdgcn_global_load_lds((const __attribute__((address_space(1))) void*)g,
                                   (__attribute__((address_space(3))) void*)l, 16, 0, 0);
}

// ---------------- edge dtype detection (int64 vs int32) ----------------
__global__ void detect_int64_kernel(const unsigned int* __restrict__ w, int E,
                                    int* __restrict__ flag) {
  __shared__ int nz;
  if (threadIdx.x == 0) nz = 0;
  __syncthreads();
  int cnt = E < 2048 ? E : 2048;
  int local = 0;
  for (int i = threadIdx.x; i < cnt; i += blockDim.x)
    if (w[2 * i + 1] != 0u) local++;
  if (local) atomicAdd(&nz, local);
  __syncthreads();
  if (threadIdx.x == 0) *flag = (nz == 0) ? 1 : 0;  // 1 => int64 layout
}

__device__ __forceinline__ void edge_at(const int* __restrict__ ew, int E, int e,
                                        int is64, int& s, int& d) {
  if (is64) { s = ew[2 * e]; d = ew[2 * E + 2 * e]; }
  else      { s = ew[e];     d = ew[E + e]; }
}

// ---------------- CSR build ----------------
__global__ void init_deg_kernel(int* deg, int N) {
  int i = blockIdx.x * blockDim.x + threadIdx.x;
  if (i < N) deg[i] = 1;  // self loop
}

__global__ void count_deg_kernel(const int* __restrict__ ew, int E, int* deg,
                                 const int* __restrict__ flag) {
  int is64 = *flag;
  int e = blockIdx.x * blockDim.x + threadIdx.x;
  if (e < E) {
    int s, d;
    edge_at(ew, E, e, is64, s, d);
    atomicAdd(&deg[d], 1);
  }
}

__global__ void scan_kernel(const int* __restrict__ deg, int* rowptr, int* cursor, int N) {
  __shared__ int sums[1024];
  int tid = threadIdx.x;
  int chunk = (N + 1023) >> 10;
  int start = tid * chunk;
  int end = start + chunk; if (end > N) end = N;
  int s = 0;
  for (int i = start; i < end; ++i) s += deg[i];
  sums[tid] = s;
  __syncthreads();
  for (int off = 1; off < 1024; off <<= 1) {
    int v = (tid >= off) ? sums[tid - off] : 0;
    __syncthreads();
    sums[tid] += v;
    __syncthreads();
  }
  int run = (tid == 0) ? 0 : sums[tid - 1];
  for (int i = start; i < end; ++i) {
    rowptr[i] = run; cursor[i] = run;
    run += deg[i];
  }
  if (tid == 1023) rowptr[N] = sums[1023];
}

__global__ void fill_kernel(const int* __restrict__ ew, int E, int N, int* cursor,
                            int* csr, const int* __restrict__ flag) {
  int is64 = *flag;
  int i = blockIdx.x * blockDim.x + threadIdx.x;
  if (i < E) {
    int s, d;
    edge_at(ew, E, i, is64, s, d);
    int pos = atomicAdd(&cursor[d], 1);
    csr[pos] = s;
  } else if (i < E + N) {
    int n = i - E;
    int pos = atomicAdd(&cursor[n], 1);
    csr[pos] = n;
  }
}

// ---------------- input conversions to split-bf16 ----------------
// x [N,256] fp32 -> A'' [N, 512] bf16 bit patterns: cols [0,256)=hi, [256,512)=lo
__global__ void convert_x_kernel(const float* __restrict__ x, short* __restrict__ A, int N) {
  int i = blockIdx.x * blockDim.x + threadIdx.x;
  if (i >= N * 256) return;
  int r = i >> 8, c = i & 255;
  float v = x[i];
  unsigned short hi = bf16_of(v);
  unsigned short lo = bf16_of(v - bf16_back(hi));
  A[(ll)r * 512 + c] = (short)hi;
  A[(ll)r * 512 + 256 + c] = (short)lo;
}

// W [K, Nc] fp32 -> Bt [Nc, 3K] bf16: segs [0,K)=W_hi^T, [K,2K)=W_lo^T, [2K,3K)=W_hi^T
__global__ __launch_bounds__(256) void convert_w_kernel(const float* __restrict__ W,
                                                        short* __restrict__ Bt,
                                                        int K, int Nc) {
  __shared__ float t[32][33];
  int k0 = blockIdx.x * 32, n0 = blockIdx.y * 32;
  int r = threadIdx.x >> 3;          // 0..31
  int c4 = (threadIdx.x & 7) * 4;    // 0..28
  float4 v = *(const float4*)&W[(ll)(k0 + r) * Nc + n0 + c4];
  t[r][c4] = v.x; t[r][c4 + 1] = v.y; t[r][c4 + 2] = v.z; t[r][c4 + 3] = v.w;
  __syncthreads();
  int K3 = 3 * K;
  short4 hp, lp;
  float f0 = t[c4 + 0][r], f1 = t[c4 + 1][r], f2 = t[c4 + 2][r], f3 = t[c4 + 3][r];
  unsigned short h0 = bf16_of(f0), h1 = bf16_of(f1), h2 = bf16_of(f2), h3 = bf16_of(f3);
  hp = make_short4((short)h0, (short)h1, (short)h2, (short)h3);
  lp = make_short4((short)bf16_of(f0 - bf16_back(h0)), (short)bf16_of(f1 - bf16_back(h1)),
                   (short)bf16_of(f2 - bf16_back(h2)), (short)bf16_of(f3 - bf16_back(h3)));
  ll base = (ll)(n0 + r) * K3 + k0 + c4;
  *(short4*)&Bt[base] = hp;
  *(short4*)&Bt[base + K] = lp;
  *(short4*)&Bt[base + 2 * K] = hp;
}

// ---------------- MFMA GEMM: C[M,Nc] fp32 = A''(split) x Bt^T ----------------
// A: [M, 2K] bf16 ([hi | lo]); Bt: [Nc, 3K] bf16; effective K' = 3K.
__global__ __launch_bounds__(256) void gemm_mfma_kernel(
    const short* __restrict__ A, const short* __restrict__ Bt,
    float* __restrict__ C, int M, int Nc, int K) {
  __shared__ char As[8192];  // [128 rows][32 bf16 = 64B]
  __shared__ char Bs[8192];  // [128 cols][32 bf16 = 64B]
  int tid = threadIdx.x;
  int bm = blockIdx.y * 128, bn = blockIdx.x * 128;
  int lane = tid & 63, wid = tid >> 6;
  int wr = wid >> 1, wc = wid & 1;  // wave quadrant
  int K2 = 2 * K, K3 = 3 * K;

  f32x4 acc[4][4];
#pragma unroll
  for (int m = 0; m < 4; ++m)
#pragma unroll
    for (int n = 0; n < 4; ++n) acc[m][n] = (f32x4){0.f, 0.f, 0.f, 0.f};

  int srow = tid >> 2;            // 0..63
  int skc = (tid & 3) * 8;        // bf16 offset within 32-wide k tile
  int ra = bm + srow;       if (ra > M - 1) ra = M - 1;
  int rb = bm + srow + 64;  if (rb > M - 1) rb = M - 1;
  const short* aP0 = A + (ll)ra * K2 + skc;
  const short* aP1 = A + (ll)rb * K2 + skc;
  const short* bP0 = Bt + (ll)(bn + srow) * K3 + skc;
  const short* bP1 = Bt + (ll)(bn + srow + 64) * K3 + skc;
  char* asDst = As + tid * 16;
  char* bsDst = Bs + tid * 16;

  const char* aF0 = As + (wr * 64 + (lane & 15)) * 64 + (lane >> 4) * 16;
  const char* bF0 = Bs + (wc * 64 + (lane & 15)) * 64 + (lane >> 4) * 16;

  for (int kt = 0; kt < K3; kt += 32) {
    int akt = kt < K ? kt : kt - K;  // hi for segs 0/1, lo for seg 2
    gload16(aP0 + akt, asDst);
    gload16(aP1 + akt, asDst + 4096);
    gload16(bP0 + kt, bsDst);
    gload16(bP1 + kt, bsDst + 4096);
    __syncthreads();
    bf16x8 af[4], bfr[4];
#pragma unroll
    for (int m = 0; m < 4; ++m) af[m] = *(const bf16x8*)(aF0 + m * 16 * 64);
#pragma unroll
    for (int n = 0; n < 4; ++n) bfr[n] = *(const bf16x8*)(bF0 + n * 16 * 64);
#pragma unroll
    for (int m = 0; m < 4; ++m)
#pragma unroll
      for (int n = 0; n < 4; ++n)
        acc[m][n] = __builtin_amdgcn_mfma_f32_16x16x32_bf16(af[m], bfr[n], acc[m][n], 0, 0, 0);
    __syncthreads();
  }

  int crow0 = bm + wr * 64 + (lane >> 4) * 4;
  int ccol0 = bn + wc * 64 + (lane & 15);
#pragma unroll
  for (int m = 0; m < 4; ++m) {
#pragma unroll
    for (int j = 0; j < 4; ++j) {
      int row = crow0 + m * 16 + j;
      if (row < M) {
#pragma unroll
        for (int n = 0; n < 4; ++n) {
          C[(ll)row * Nc + ccol0 + n * 16] = acc[m][n][j];
        }
      }
    }
  }
}

// ---------------- per-node attention scores (float4) ----------------
__global__ void score_kernel(const float* __restrict__ h, const float* __restrict__ a_src,
                             const float* __restrict__ a_dst, float* __restrict__ s_src,
                             float* __restrict__ s_dst, int N, int dout) {
  int wid = threadIdx.x >> 6;
  int lane = threadIdx.x & 63;
  int row = blockIdx.x * (blockDim.x >> 6) + wid;
  if (row >= N) return;
  const float4* hr = (const float4*)(h + (ll)row * dout);
  const float4* as4 = (const float4*)a_src;
  const float4* ad4 = (const float4*)a_dst;
  float ss = 0.f, sd = 0.f;
  int nv = dout >> 2;
  for (int d = lane; d < nv; d += 64) {
    float4 v = hr[d], a = as4[d], b = ad4[d];
    ss += v.x * a.x + v.y * a.y + v.z * a.z + v.w * a.w;
    sd += v.x * b.x + v.y * b.y + v.z * b.z + v.w * b.w;
  }
#pragma unroll
  for (int o = 32; o > 0; o >>= 1) {
    ss += __shfl_xor(ss, o, 64);
    sd += __shfl_xor(sd, o, 64);
  }
  if (lane == 0) { s_src[row] = ss; s_dst[row] = sd; }
}

// ---------------- segment softmax + weighted aggregation (per node) ----------------
// outH != nullptr: write split-bf16 [node, 2*dout] ([hi|lo], post-bias/ReLU) for next GEMM
// outF != nullptr: write fp32 (final layer)
__global__ __launch_bounds__(256) void aggregate_kernel(
    const float* __restrict__ h, const float* __restrict__ ssrc,
    const float* __restrict__ sdst, const int* __restrict__ rowptr,
    const int* __restrict__ csr, const float* __restrict__ bias,
    float* __restrict__ outF, short* __restrict__ outH, int dout, int do_relu) {
  int node = blockIdx.x;
  int tid = threadIdx.x;
  int lane = tid & 63, wid = tid >> 6;
  int rs = rowptr[node], re = rowptr[node + 1];
  float sd = sdst[node];
  __shared__ float red[4];

  // pass 1: max logit
  float m = -1e30f;
  for (int i = rs + tid; i < re; i += 256) {
    float e = ssrc[csr[i]] + sd;
    e = e > 0.f ? e : NEG_SLOPE * e;
    m = fmaxf(m, e);
  }
#pragma unroll
  for (int o = 32; o > 0; o >>= 1) m = fmaxf(m, __shfl_xor(m, o, 64));
  if (lane == 0) red[wid] = m;
  __syncthreads();
  m = fmaxf(fmaxf(red[0], red[1]), fmaxf(red[2], red[3]));
  __syncthreads();

  // pass 2: denominator
  float den = 0.f;
  for (int i = rs + tid; i < re; i += 256) {
    float e = ssrc[csr[i]] + sd;
    e = e > 0.f ? e : NEG_SLOPE * e;
    den += __expf(e - m);
  }
#pragma unroll
  for (int o = 32; o > 0; o >>= 1) den += __shfl_xor(den, o, 64);
  if (lane == 0) red[wid] = den;
  __syncthreads();
  den = red[0] + red[1] + red[2] + red[3];
  float inv = 1.f / (den + EPS_F);

  // pass 3: weighted accumulate (float4 per thread)
  int d = tid * 4;
  bool act = d < dout;
  float ax = 0.f, ay = 0.f, az = 0.f, aw = 0.f;
  for (int i = rs; i < re; ++i) {
    int s = csr[i];
    float e = ssrc[s] + sd;
    e = e > 0.f ? e : NEG_SLOPE * e;
    float w = __expf(e - m) * inv;
    if (act) {
      float4 hv = *(const float4*)&h[(ll)s * dout + d];
      ax += w * hv.x; ay += w * hv.y; az += w * hv.z; aw += w * hv.w;
    }
  }
  if (act) {
    float4 bv = *(const float4*)&bias[d];
    float vx = ax + bv.x, vy = ay + bv.y, vz = az + bv.z, vw = aw + bv.w;
    if (do_relu) {
      vx = fmaxf(vx, 0.f); vy = fmaxf(vy, 0.f);
      vz = fmaxf(vz, 0.f); vw = fmaxf(vw, 0.f);
    }
    if (outH) {
      unsigned short h0 = bf16_of(vx), h1 = bf16_of(vy), h2 = bf16_of(vz), h3 = bf16_of(vw);
      short4 hp = make_short4((short)h0, (short)h1, (short)h2, (short)h3);
      short4 lp = make_short4((short)bf16_of(vx - bf16_back(h0)),
                              (short)bf16_of(vy - bf16_back(h1)),
                              (short)bf16_of(vz - bf16_back(h2)),
                              (short)bf16_of(vw - bf16_back(h3)));
      ll base = (ll)node * (2 * dout) + d;
      *(short4*)&outH[base] = hp;
      *(short4*)&outH[base + dout] = lp;
    } else {
      *(float4*)&outF[(ll)node * dout + d] = make_float4(vx, vy, vz, vw);
    }
  }
}

// ---------------- row log_softmax (C == blockDim.x) ----------------
__global__ void log_softmax_kernel(const float* __restrict__ in, float* __restrict__ out,
                                   int C) {
  int row = blockIdx.x;
  int tid = threadIdx.x;
  int lane = tid & 63, wid = tid >> 6;
  __shared__ float red[2];
  float v = in[(ll)row * C + tid];
  float m = v;
#pragma unroll
  for (int o = 32; o > 0; o >>= 1) m = fmaxf(m, __shfl_xor(m, o, 64));
  if (lane == 0) red[wid] = m;
  __syncthreads();
  m = fmaxf(red[0], red[1]);
  __syncthreads();
  float ex = __expf(v - m);
  float s = ex;
#pragma unroll
  for (int o = 32; o > 0; o >>= 1) s += __shfl_xor(s, o, 64);
  if (lane == 0) red[wid] = s;
  __syncthreads();
  s = red[0] + red[1];
  out[(ll)row * C + tid] = v - m - logf(s);
}

// ---------------- launch ----------------
extern "C" void kernel_launch(void* const* d_in, const int* in_sizes, int n_in,
                              void* d_out, int out_size, void* d_ws, size_t ws_size,
                              hipStream_t stream) {
  const float* x = (const float*)d_in[0];
  const int* ew = (const int*)d_in[1];
  int N = in_sizes[0] / 256;
  int E = in_sizes[1] / 2;

  const float* W[4]   = {(const float*)d_in[2],  (const float*)d_in[6],
                         (const float*)d_in[10], (const float*)d_in[14]};
  const float* Asv[4] = {(const float*)d_in[3],  (const float*)d_in[7],
                         (const float*)d_in[11], (const float*)d_in[15]};
  const float* Adv[4] = {(const float*)d_in[4],  (const float*)d_in[8],
                         (const float*)d_in[12], (const float*)d_in[16]};
  const float* Bv[4]  = {(const float*)d_in[5],  (const float*)d_in[9],
                         (const float*)d_in[13], (const float*)d_in[17]};
  const int din[4]  = {256, 1024, 1024, 512};
  const int dout[4] = {1024, 1024, 512, 128};

  char* ws = (char*)d_ws;
  size_t off = 0;
  auto alloc = [&](size_t bytes) {
    void* p = ws + off;
    off += (bytes + 255) & ~(size_t)255;
    return p;
  };
  float* h    = (float*)alloc((size_t)N * 1024 * 4);
  short* bufP = (short*)alloc((size_t)N * 2048 * 2);
  short* bufQ = (short*)alloc((size_t)N * 2048 * 2);
  float* sF   = (float*)alloc((size_t)N * 128 * 4);
  float* s_src = (float*)alloc((size_t)N * 4);
  float* s_dst = (float*)alloc((size_t)N * 4);
  int* deg    = (int*)alloc((size_t)(N + 1) * 4);
  int* rowptr = (int*)alloc((size_t)(N + 1) * 4);
  int* cursor = (int*)alloc((size_t)(N + 1) * 4);
  int* csr    = (int*)alloc((size_t)(E + N) * 4);
  int* flag   = (int*)alloc(256);
  short* Bt[4];
  for (int l = 0; l < 4; ++l) Bt[l] = (short*)alloc((size_t)dout[l] * 3 * din[l] * 2);

  detect_int64_kernel<<<1, 256, 0, stream>>>((const unsigned int*)ew, E, flag);
  init_deg_kernel<<<(N + 255) / 256, 256, 0, stream>>>(deg, N);
  count_deg_kernel<<<(E + 255) / 256, 256, 0, stream>>>(ew, E, deg, flag);
  scan_kernel<<<1, 1024, 0, stream>>>(deg, rowptr, cursor, N);
  fill_kernel<<<(E + N + 255) / 256, 256, 0, stream>>>(ew, E, N, cursor, csr, flag);

  convert_x_kernel<<<(N * 256 + 255) / 256, 256, 0, stream>>>(x, bufP, N);
  for (int l = 0; l < 4; ++l) {
    dim3 cg(din[l] / 32, dout[l] / 32);
    convert_w_kernel<<<cg, 256, 0, stream>>>(W[l], Bt[l], din[l], dout[l]);
  }

  short* cur = bufP;
  short* nxt = bufQ;
  for (int l = 0; l < 4; ++l) {
    dim3 ggrid(dout[l] / 128, (N + 127) / 128);
    gemm_mfma_kernel<<<ggrid, 256, 0, stream>>>(cur, Bt[l], h, N, dout[l], din[l]);
    score_kernel<<<(N + 3) / 4, 256, 0, stream>>>(h, Asv[l], Adv[l], s_src, s_dst,
                                                  N, dout[l]);
    if (l < 3) {
      aggregate_kernel<<<N, 256, 0, stream>>>(h, s_src, s_dst, rowptr, csr, Bv[l],
                                              nullptr, nxt, dout[l], 1);
    } else {
      aggregate_kernel<<<N, 256, 0, stream>>>(h, s_src, s_dst, rowptr, csr, Bv[l],
                                              sF, nullptr, dout[l], 0);
    }
    short* t = cur; cur = nxt; nxt = t;
  }
  log_softmax_kernel<<<N, 128, 0, stream>>>(sF, (float*)d_out, 128);
}